// Round 7
// baseline (44.813 us; speedup 1.0000x reference)
//
#include <hip/hip_runtime.h>
#include <stdint.h>

typedef unsigned short u16;
typedef __attribute__((ext_vector_type(4))) u16    u16x4;
typedef __attribute__((ext_vector_type(8))) u16    u16x8;
typedef __attribute__((ext_vector_type(4))) float  f32x4;
typedef __attribute__((ext_vector_type(8))) __bf16 bf16x8;

union BF8 { u16x8 u; bf16x8 b; };

__device__ __forceinline__ u16 f2bf(float f) {
    union { float f; uint32_t u; } v; v.f = f;
    uint32_t u = v.u;
    uint32_t rb = 0x7FFFu + ((u >> 16) & 1u);
    return (u16)((u + rb) >> 16);
}

// ---------------- kernel 0: W[k][f] -> Wt[f][k] bf16 ----------------
__global__ __launch_bounds__(256) void gcn_wt(const float* __restrict__ W,
                                              u16* __restrict__ Wt) {
    int idx = blockIdx.x * 256 + threadIdx.x;   // 0..16383
    int k = idx >> 7, f = idx & 127;
    Wt[f * 128 + k] = f2bf(W[idx]);
}

// ---------------- kernel 1: hT[b][f][n] = bf16((x@W)^T + b) ----------------
// (proven round-2 structure)
__global__ __launch_bounds__(256) void gcn_xw(const float* __restrict__ x,
                                              const u16* __restrict__ Wt,
                                              const float* __restrict__ bias,
                                              u16* __restrict__ hT) {
    __shared__ u16 Wl[128 * 128];   // [f][k] swizzled (256B rows)
    __shared__ u16 Xl[128 * 128];   // [n][k] swizzled (256B rows)
    const int t  = threadIdx.x;
    const int bb = blockIdx.x >> 3;
    const int n0 = (blockIdx.x & 7) << 7;

#pragma unroll
    for (int i = 0; i < 16; ++i) {
        int o  = i * 256 + t;
        int f  = o >> 5;
        int kb = (o & 31) * 8;
        u16x4 v = *(const u16x4*)((const char*)Wt + o * 8);
        *(u16x4*)((char*)Wl + f * 256 + (kb ^ ((f & 7) << 4))) = v;
    }
    const float* xb = x + (size_t)bb * (1024 * 128) + (size_t)n0 * 128;
#pragma unroll
    for (int i = 0; i < 16; ++i) {
        int o4 = i * 256 + t;
        int n  = o4 >> 5;
        int kb = (o4 & 31) * 8;
        f32x4 v = *(const f32x4*)(xb + (size_t)o4 * 4);
        u16x4 h; h.x = f2bf(v.x); h.y = f2bf(v.y); h.z = f2bf(v.z); h.w = f2bf(v.w);
        *(u16x4*)((char*)Xl + n * 256 + (kb ^ ((n & 7) << 4))) = h;
    }
    __syncthreads();

    const int w = t >> 6, l = t & 63;
    const int wr = w >> 1, wc = w & 1;
    f32x4 acc[4][4] = {};
#pragma unroll
    for (int kk = 0; kk < 4; ++kk) {
        const int kbyte = kk * 64 + (l >> 4) * 16;
        bf16x8 a[4], b[4];
#pragma unroll
        for (int mf = 0; mf < 4; ++mf) {
            int fl = wr * 64 + mf * 16 + (l & 15);
            a[mf] = *(const bf16x8*)((const char*)Wl + fl * 256 + (kbyte ^ ((fl & 7) << 4)));
        }
#pragma unroll
        for (int nn = 0; nn < 4; ++nn) {
            int nl = wc * 64 + nn * 16 + (l & 15);
            b[nn] = *(const bf16x8*)((const char*)Xl + nl * 256 + (kbyte ^ ((nl & 7) << 4)));
        }
#pragma unroll
        for (int mf = 0; mf < 4; ++mf)
#pragma unroll
            for (int nn = 0; nn < 4; ++nn)
                acc[mf][nn] = __builtin_amdgcn_mfma_f32_16x16x32_bf16(
                    a[mf], b[nn], acc[mf][nn], 0, 0, 0);
    }

    u16* ho = hT + (size_t)bb * 131072;
#pragma unroll
    for (int mf = 0; mf < 4; ++mf) {
        int fbase = wr * 64 + mf * 16 + (l >> 4) * 4;
#pragma unroll
        for (int r = 0; r < 4; ++r) {
            float bv = bias[fbase + r];
#pragma unroll
            for (int nn = 0; nn < 4; ++nn) {
                int n = wc * 64 + nn * 16 + (l & 15);
                ho[(size_t)(fbase + r) * 1024 + n0 + n] = f2bf(acc[mf][nn][r] + bv);
            }
        }
    }
}

// ---------------- kernel 2: out = relu(adj @ h + x) ----------------
// Lean agg: LDS = adj A-tile double-buffer only (16 KB) -> 4 blocks/CU.
// B-frags loaded directly from global hT (L2-hot, 64B-line per f-row),
// prefetched depth-1 in registers. 512 thr = 8 waves, wave = 64r x 16f.
__global__ __launch_bounds__(512, 4) void gcn_agg(const float* __restrict__ adj,
                                                  const u16* __restrict__ hT,
                                                  const float* __restrict__ x,
                                                  float* __restrict__ out) {
    __shared__ u16 Al[2][64 * 64];      // bf16 adj tile, 8 KB each, XOR-swizzled

    const int t = threadIdx.x;          // 0..511
    // bijective XCD swizzle: 64 blocks/XCD; one XCD owns 4 whole batches
    const int L  = (blockIdx.x & 7) * 64 + (blockIdx.x >> 3);
    const int bb = L >> 4;
    const int r0 = (L & 15) << 6;

    const float* adjb = adj + (size_t)bb * 1048576 + (size_t)r0 * 1024;
    const u16*   hTb  = hT + (size_t)bb * 131072;

    const int w = t >> 6, l = t & 63;
    const int lc = l & 15, lg = l >> 4;
    const int f = w * 16 + lc;          // this wave's feature column (per lane)

    // A staging: row rA = t>>3 (8 threads/row), 8 floats each
    const int rA = t >> 3, k8 = t & 7;
    const float* gA = adjb + (size_t)rA * 1024 + k8 * 8;
    const int ldsA = rA * 128 + ((k8 * 16) ^ ((rA & 7) << 4));

    // B frags: lane reads hT[f][n0 + kn*32 + lg*8 .. +8] (16B)
    const u16* gB = hTb + (size_t)f * 1024 + lg * 8;

#define LOADA(ar, ks)                                 \
    do {                                              \
        ar[0] = *(const f32x4*)(gA + (ks) * 64);      \
        ar[1] = *(const f32x4*)(gA + (ks) * 64 + 4);  \
    } while (0)

#define LOADB(br, ks)                                          \
    do {                                                       \
        br[0] = *(const u16x8*)(gB + (ks) * 64);               \
        br[1] = *(const u16x8*)(gB + (ks) * 64 + 32);          \
    } while (0)

#define WRITEA(buf, ar)                                 \
    do {                                                \
        u16x8 ha;                                       \
        ha[0] = f2bf(ar[0].x); ha[1] = f2bf(ar[0].y);   \
        ha[2] = f2bf(ar[0].z); ha[3] = f2bf(ar[0].w);   \
        ha[4] = f2bf(ar[1].x); ha[5] = f2bf(ar[1].y);   \
        ha[6] = f2bf(ar[1].z); ha[7] = f2bf(ar[1].w);   \
        *(u16x8*)((char*)&Al[buf][0] + ldsA) = ha;      \
    } while (0)

// lgkmcnt drain + barrier; global prefetch (vmcnt) stays in flight.
#define BARRIER() asm volatile("s_waitcnt lgkmcnt(0)\ns_barrier" ::: "memory")

#define COMPUTE(buf, br)                                                        \
    do {                                                                        \
        _Pragma("unroll")                                                       \
        for (int kn = 0; kn < 2; ++kn) {                                        \
            BF8 bu; bu.u = br[kn];                                              \
            _Pragma("unroll")                                                   \
            for (int rb = 0; rb < 4; ++rb) {                                    \
                int r = rb * 16 + lc;                                           \
                bf16x8 a = *(const bf16x8*)((const char*)&Al[buf][0] + r * 128  \
                               + ((kn * 64 + lg * 16) ^ ((r & 7) << 4)));       \
                yacc[rb] = __builtin_amdgcn_mfma_f32_16x16x32_bf16(             \
                    a, bu.b, yacc[rb], 0, 0, 0);                                \
            }                                                                   \
        }                                                                       \
    } while (0)

    f32x4 yacc[4] = {};
    f32x4 aCur[2], aNxt[2];
    u16x8 bCur[2], bNxt[2];

    LOADA(aCur, 0);
    LOADB(bCur, 0);
#pragma unroll
    for (int ks = 0; ks < 16; ++ks) {
        const int buf = ks & 1;
        WRITEA(buf, aCur);
        BARRIER();
        if (ks + 1 < 16) {
            LOADA(aNxt, ks + 1);     // flies over COMPUTE
            LOADB(bNxt, ks + 1);
        }
        COMPUTE(buf, bCur);
        aCur[0] = aNxt[0]; aCur[1] = aNxt[1];
        bCur[0] = bNxt[0]; bCur[1] = bNxt[1];
    }
#undef LOADA
#undef LOADB
#undef WRITEA
#undef BARRIER
#undef COMPUTE

    // epilogue: + x, relu, fp32 store
    const float* xb = x + (size_t)bb * 131072 + (size_t)r0 * 128;
    float*       ob = out + (size_t)bb * 131072 + (size_t)r0 * 128;
#pragma unroll
    for (int rb = 0; rb < 4; ++rb)
#pragma unroll
        for (int j = 0; j < 4; ++j) {
            int rr = rb * 16 + lg * 4 + j;
            size_t idx = (size_t)rr * 128 + f;
            float v = yacc[rb][j] + xb[idx];
            ob[idx] = fmaxf(v, 0.0f);
        }
}

extern "C" void kernel_launch(void* const* d_in, const int* in_sizes, int n_in,
                              void* d_out, int out_size, void* d_ws, size_t ws_size,
                              hipStream_t stream) {
    const float* x    = (const float*)d_in[0];
    const float* adj  = (const float*)d_in[1];
    const float* W    = (const float*)d_in[2];
    const float* bias = (const float*)d_in[3];
    float* out = (float*)d_out;

    u16* hT = (u16*)d_ws;                                    // 8 MiB
    u16* Wt = (u16*)((char*)d_ws + (size_t)32 * 131072 * 2); // +32 KiB

    gcn_wt <<<dim3(64),  dim3(256), 0, stream>>>(W, Wt);
    gcn_xw <<<dim3(256), dim3(256), 0, stream>>>(x, Wt, bias, hT);
    gcn_agg<<<dim3(512), dim3(512), 0, stream>>>(adj, hT, x, out);
}